// Round 3
// baseline (360.479 us; speedup 1.0000x reference)
//
#include <hip/hip_runtime.h>
#include <hip/hip_bf16.h>
#include <cstdint>
#include <cstddef>

#define N 8192
#define F 64
#define NEMB 128
#define BI 16
#define BJ 256
#define NBLK (N/BI)
#define LEAKY 0.01f

typedef __attribute__((ext_vector_type(8))) short bf16x8;
typedef __attribute__((ext_vector_type(4))) float f32x4;

__device__ __forceinline__ float wave_reduce_sum_f(float v){
  #pragma unroll
  for (int d = 32; d > 0; d >>= 1) v += __shfl_xor(v, d, 64);
  return v;
}
__device__ __forceinline__ int wave_reduce_sum_i(int v){
  #pragma unroll
  for (int d = 32; d > 0; d >>= 1) v += __shfl_xor(v, d, 64);
  return v;
}
__device__ __forceinline__ unsigned short f2bf(float x){
  union { float f; unsigned u; } v; v.f = x;
  unsigned r = v.u + 0x7fff + ((v.u >> 16) & 1);
  return (unsigned short)(r >> 16);
}

// Kernel A: h = x @ W^T + b; s_src/s_dst; block 0 also zeroes lookback state
extern "C" __global__ void __launch_bounds__(256)
k_h(const float* __restrict__ x, const float* __restrict__ ww, const float* __restrict__ wb,
    const float* __restrict__ aw, float* __restrict__ h,
    float* __restrict__ ssrc, float* __restrict__ sdst,
    unsigned* __restrict__ partials, int* __restrict__ ticket){
  const int t = threadIdx.x, w = t >> 6, lane = t & 63;
  if (blockIdx.x == 0){
    partials[t] = 0; partials[t + 256] = 0;
    if (t == 0) *ticket = 0;
  }
  __shared__ float xs[4][NEMB];
  const int n0 = blockIdx.x * 4;
  ((float2*)&xs[0][0])[t] = ((const float2*)(x + (size_t)n0 * NEMB))[t];
  __syncthreads();
  const int n = n0 + w;
  const float4* w4 = (const float4*)(ww + (size_t)lane * NEMB);
  const float4* x4 = (const float4*)&xs[w][0];
  float acc = wb[lane];
  #pragma unroll
  for (int k = 0; k < NEMB/4; ++k){
    float4 a = x4[k]; float4 b = w4[k];
    acc = fmaf(a.x, b.x, acc);
    acc = fmaf(a.y, b.y, acc);
    acc = fmaf(a.z, b.z, acc);
    acc = fmaf(a.w, b.w, acc);
  }
  h[(size_t)n * F + lane] = acc;
  float vs = wave_reduce_sum_f(acc * aw[lane]);
  float vd = wave_reduce_sum_f(acc * aw[F + lane]);
  if (lane == 0){ ssrc[n] = vs; sdst[n] = vd; }
}

// Kernel A2: transpose h (fp32 [N][F]) -> ht (bf16 [F][N])
extern "C" __global__ void __launch_bounds__(256)
k_tr(const float* __restrict__ h, unsigned short* __restrict__ ht){
  __shared__ float tile[64][65];
  const int t = threadIdx.x;
  const int n0 = blockIdx.x * 64;
  #pragma unroll
  for (int s = 0; s < 4; ++s){
    const int r = s*16 + (t>>4);
    const int c = (t&15)*4;
    const float4 v = *(const float4*)(h + (size_t)(n0+r)*F + c);
    tile[r][c] = v.x; tile[r][c+1] = v.y; tile[r][c+2] = v.z; tile[r][c+3] = v.w;
  }
  __syncthreads();
  const int f = t >> 2, jq = t & 3;
  unsigned short buf[16];
  #pragma unroll
  for (int k = 0; k < 16; ++k) buf[k] = f2bf(tile[jq*16 + k][f]);
  *(uint4*)(ht + (size_t)f*N + n0 + jq*16)     = *(uint4*)&buf[0];
  *(uint4*)(ht + (size_t)f*N + n0 + jq*16 + 8) = *(uint4*)&buf[8];
}

// Fused kernel: adj read+pack (LDS) -> decoupled-lookback rank base -> chunked
// exp-logits -> bf16 p -> MFMA att@h -> elu.
// 256 thr (4 waves), BI=16 rows/block, ticket-ordered vid for lookback safety.
extern "C" __global__ void __launch_bounds__(256, 2)
k_main(const int* __restrict__ adj, const unsigned short* __restrict__ ht,
       const float* __restrict__ ssrc, const float* __restrict__ sdst,
       const float* __restrict__ abias,
       unsigned* __restrict__ partials, int* __restrict__ ticket,
       float* __restrict__ out){
  __shared__ __attribute__((aligned(16))) char ht_lds[64*512]; // 32 KB swizzled
  __shared__ __attribute__((aligned(16))) char pt_lds[16*512]; // 8 KB swizzled
  __shared__ unsigned short bm_lds[BI][N/16];                  // 16 KB masks
  __shared__ float denom_lds[BI];
  __shared__ int cnt_lds[BI];
  __shared__ int base_lds[BI];
  __shared__ int vid_s, gbase_s;

  const int t = threadIdx.x, w = t >> 6, lane = t & 63;
  if (t == 0) vid_s = atomicAdd(ticket, 1);
  __syncthreads();
  const int vid = vid_s;
  const int i0 = vid * BI;

  // ---- sweep 1: read 16 adj rows once, pack bitmask to LDS, per-row counts ----
  #pragma unroll
  for (int rr = 0; rr < 4; ++rr){
    const int i = i0 + w*4 + rr;
    const int4* row4 = (const int4*)(adj + (size_t)i * N);
    int rcnt = 0;
    #pragma unroll 4
    for (int it = 0; it < 32; ++it){
      const int4 a = row4[it*64 + lane];
      unsigned nib = (unsigned)(a.x>0) | ((unsigned)(a.y>0)<<1) |
                     ((unsigned)(a.z>0)<<2) | ((unsigned)(a.w>0)<<3);
      rcnt += __popc(nib);
      unsigned word = nib << ((lane & 3) * 4);
      word |= __shfl_xor(word, 1, 64);
      word |= __shfl_xor(word, 2, 64);
      if ((lane & 3) == 0) bm_lds[w*4+rr][it*16 + (lane>>2)] = (unsigned short)word;
    }
    rcnt = wave_reduce_sum_i(rcnt);
    if (lane == 0) cnt_lds[w*4+rr] = rcnt;
  }
  __syncthreads();

  // ---- block scan + decoupled lookback (thread 0) ----
  if (t == 0){
    int run = 0;
    #pragma unroll
    for (int k = 0; k < BI; ++k){ int c = cnt_lds[k]; base_lds[k] = run; run += c; }
    const unsigned pub = ((unsigned)run << 2) | (vid == 0 ? 2u : 1u);
    __hip_atomic_store(&partials[vid], pub, __ATOMIC_RELEASE, __HIP_MEMORY_SCOPE_AGENT);
    unsigned long long excl = 0;
    if (vid > 0){
      int look = vid - 1;
      while (1){
        unsigned v;
        do {
          v = __hip_atomic_load(&partials[look], __ATOMIC_ACQUIRE, __HIP_MEMORY_SCOPE_AGENT);
        } while (!(v & 3u));
        excl += (v >> 2);
        if ((v & 3u) == 2u) break;
        --look;
      }
      __hip_atomic_store(&partials[vid],
                         (unsigned)(((excl + (unsigned long long)(unsigned)run) << 2) | 2u),
                         __ATOMIC_RELEASE, __HIP_MEMORY_SCOPE_AGENT);
    }
    gbase_s = (int)excl;
  }
  __syncthreads();

  const int r = t >> 4, g = t & 15;
  const float ab = abias[0];
  int rank = gbase_s + base_lds[r];
  float dsum = 0.f;
  f32x4 acc = {0.f, 0.f, 0.f, 0.f};

  const int fr = lane & 15, ks = lane >> 4;
  const int fB = w*16 + fr;
  const char* aBase = pt_lds + fr*512;
  const char* bBase = ht_lds + fB*512;
  const int sA = (fr & 7) << 4;
  const int sB = (fB & 7) << 4;

  for (int j0 = 0; j0 < N; j0 += BJ){
    __syncthreads();
    // stage ht chunk (bf16 [64][256], swizzled) via global_load_lds
    #pragma unroll
    for (int k = 0; k < 8; ++k){
      const int L = (w*8 + k) * 1024;
      const int f = (w*8 + k) * 2 + (lane >> 5);
      const int b = (lane & 31) * 16;
      const char* src = (const char*)ht + (size_t)f*(N*2) + j0*2 + (b ^ ((f & 7) << 4));
      __builtin_amdgcn_global_load_lds((const __attribute__((address_space(1))) void*)src,
                                       (__attribute__((address_space(3))) void*)(ht_lds + L),
                                       16, 0, 0);
    }
    // p production: independent per-bit ranks (popc-prefix) -> exp -> bf16 -> LDS
    {
      const unsigned m = bm_lds[r][(j0 >> 4) + g];
      const int c = __popc(m);
      int inc = c;
      #pragma unroll
      for (int d = 1; d < 16; d <<= 1){
        int u = __shfl_up(inc, d, 16);
        if (g >= d) inc += u;
      }
      const int rowtot = __shfl(inc, 15, 16);
      const int q0 = rank + inc - c;
      rank += rowtot;
      unsigned pk[8];
      #pragma unroll
      for (int bb = 0; bb < 16; ++bb){
        float p = 0.f;
        if ((m >> bb) & 1u){
          const int qb = q0 + __popc(m & ((1u << bb) - 1u));
          float e = ssrc[qb >> 13] + sdst[qb & (N - 1)] + ab;
          e = (e > 0.f) ? e : LEAKY * e;
          p = __expf(e);
          dsum += p;
        }
        if (bb & 1) pk[bb >> 1] |= (unsigned)f2bf(p) << 16;
        else        pk[bb >> 1]  = (unsigned)f2bf(p);
      }
      char* pb = pt_lds + r*512;
      const int sw = (r & 7) << 4;
      *(uint4*)(pb + ((g*32)      ^ sw)) = make_uint4(pk[0], pk[1], pk[2], pk[3]);
      *(uint4*)(pb + ((g*32 + 16) ^ sw)) = make_uint4(pk[4], pk[5], pk[6], pk[7]);
    }
    __syncthreads();
    // MFMA: 8 K-steps of 16x16x32
    #pragma unroll
    for (int kk = 0; kk < 8; ++kk){
      const int off = kk*64 + ks*16;
      bf16x8 av = *(const bf16x8*)(aBase + (off ^ sA));
      bf16x8 bv = *(const bf16x8*)(bBase + (off ^ sB));
      acc = __builtin_amdgcn_mfma_f32_16x16x32_bf16(av, bv, acc, 0, 0, 0);
    }
  }
  // denominators
  #pragma unroll
  for (int d = 8; d > 0; d >>= 1) dsum += __shfl_xor(dsum, d, 16);
  if (g == 0) denom_lds[r] = dsum;
  __syncthreads();
  // epilogue: C/D layout col=lane&15, row=(lane>>4)*4+reg
  #pragma unroll
  for (int reg = 0; reg < 4; ++reg){
    const int il = ks*4 + reg;
    const float dn = denom_lds[il];
    float v = (dn > 0.f) ? acc[reg] / dn : 0.f;
    const float o = (v > 0.f) ? v : (__expf(v) - 1.f);
    out[(size_t)(i0 + il)*F + w*16 + fr] = o;
  }
}

extern "C" void kernel_launch(void* const* d_in, const int* in_sizes, int n_in,
                              void* d_out, int out_size, void* d_ws, size_t ws_size,
                              hipStream_t stream){
  const float* x   = (const float*)d_in[0];
  const int*   adj = (const int*)d_in[1];
  const float* ww  = (const float*)d_in[2];
  const float* wb  = (const float*)d_in[3];
  const float* aw  = (const float*)d_in[4];
  const float* ab  = (const float*)d_in[5];
  float* out = (float*)d_out;

  char* ws = (char*)d_ws;
  float*          h        = (float*)(ws);                                  // 2 MB
  unsigned short* ht       = (unsigned short*)(ws + (size_t)N*F*4);         // 1 MB
  float*          ssrc     = (float*)(ws + (size_t)N*F*4 + (size_t)N*F*2);  // 32 KB
  float*          sdst     = ssrc + N;                                      // 32 KB
  unsigned*       partials = (unsigned*)(sdst + N);                         // 2 KB
  int*            ticket   = (int*)(partials + NBLK);                       // 4 B

  k_h   <<<N/4,  256, 0, stream>>>(x, ww, wb, aw, h, ssrc, sdst, partials, ticket);
  k_tr  <<<N/64, 256, 0, stream>>>(h, ht);
  k_main<<<NBLK, 256, 0, stream>>>(adj, ht, ssrc, sdst, ab, partials, ticket, out);
}

// Round 4
// 267.586 us; speedup vs baseline: 1.3472x; 1.3472x over previous
//
#include <hip/hip_runtime.h>
#include <cstdint>
#include <cstddef>

#define N 8192
#define F 64
#define NEMB 128
#define BI 16
#define BJ 256
#define NCHUNK (N/BJ)   // 32
#define NBLK (N/BI)     // 512
#define LEAKY 0.01f

typedef __attribute__((ext_vector_type(8))) short bf16x8;
typedef __attribute__((ext_vector_type(4))) float f32x4;

__device__ __forceinline__ float wave_reduce_sum_f(float v){
  #pragma unroll
  for (int d = 32; d > 0; d >>= 1) v += __shfl_xor(v, d, 64);
  return v;
}
__device__ __forceinline__ int wave_reduce_sum_i(int v){
  #pragma unroll
  for (int d = 32; d > 0; d >>= 1) v += __shfl_xor(v, d, 64);
  return v;
}
__device__ __forceinline__ unsigned short f2bf(float x){
  union { float f; unsigned u; } v; v.f = x;
  unsigned r = v.u + 0x7fff + ((v.u >> 16) & 1);
  return (unsigned short)(r >> 16);
}

// Kernel A: h = x @ W^T + b; ssrc; sdst duplicated x2 (wrap-free windows);
// block 0 zeroes lookback state.
extern "C" __global__ void __launch_bounds__(256)
k_h(const float* __restrict__ x, const float* __restrict__ ww, const float* __restrict__ wb,
    const float* __restrict__ aw, float* __restrict__ h,
    float* __restrict__ ssrc, float* __restrict__ sdst2x,
    unsigned* __restrict__ partials, int* __restrict__ ticket){
  const int t = threadIdx.x, w = t >> 6, lane = t & 63;
  if (blockIdx.x == 0){
    partials[t] = 0; partials[t + 256] = 0;
    if (t == 0) *ticket = 0;
  }
  __shared__ float xs[4][NEMB];
  const int n0 = blockIdx.x * 4;
  ((float2*)&xs[0][0])[t] = ((const float2*)(x + (size_t)n0 * NEMB))[t];
  __syncthreads();
  const int n = n0 + w;
  const float4* w4 = (const float4*)(ww + (size_t)lane * NEMB);
  const float4* x4 = (const float4*)&xs[w][0];
  float acc = wb[lane];
  #pragma unroll
  for (int k = 0; k < NEMB/4; ++k){
    float4 a = x4[k]; float4 b = w4[k];
    acc = fmaf(a.x, b.x, acc);
    acc = fmaf(a.y, b.y, acc);
    acc = fmaf(a.z, b.z, acc);
    acc = fmaf(a.w, b.w, acc);
  }
  h[(size_t)n * F + lane] = acc;
  float vs = wave_reduce_sum_f(acc * aw[lane]);
  float vd = wave_reduce_sum_f(acc * aw[F + lane]);
  if (lane == 0){ ssrc[n] = vs; sdst2x[n] = vd; sdst2x[n + N] = vd; }
}

// Kernel A2: transpose h (fp32 [N][F]) -> ht (bf16 [F][N])
extern "C" __global__ void __launch_bounds__(256)
k_tr(const float* __restrict__ h, unsigned short* __restrict__ ht){
  __shared__ float tile[64][65];
  const int t = threadIdx.x;
  const int n0 = blockIdx.x * 64;
  #pragma unroll
  for (int s = 0; s < 4; ++s){
    const int r = s*16 + (t>>4);
    const int c = (t&15)*4;
    const float4 v = *(const float4*)(h + (size_t)(n0+r)*F + c);
    tile[r][c] = v.x; tile[r][c+1] = v.y; tile[r][c+2] = v.z; tile[r][c+3] = v.w;
  }
  __syncthreads();
  const int f = t >> 2, jq = t & 3;
  unsigned short buf[16];
  #pragma unroll
  for (int k = 0; k < 16; ++k) buf[k] = f2bf(tile[jq*16 + k][f]);
  *(uint4*)(ht + (size_t)f*N + n0 + jq*16)     = *(uint4*)&buf[0];
  *(uint4*)(ht + (size_t)f*N + n0 + jq*16 + 8) = *(uint4*)&buf[8];
}

// Fused: adj read+pack -> per-chunk rank table -> PARALLEL lookback ->
// chunked sdst-window staging + exp logits -> bf16 p -> MFMA att@h -> elu
extern "C" __global__ void __launch_bounds__(256, 2)
k_main(const int* __restrict__ adj, const unsigned short* __restrict__ ht,
       const float* __restrict__ ssrc, const float* __restrict__ sdst2x,
       const float* __restrict__ abias,
       unsigned* __restrict__ partials, int* __restrict__ ticket,
       float* __restrict__ out){
  __shared__ __attribute__((aligned(16))) char ht_lds[64*512];     // 32 KB swizzled
  __shared__ __attribute__((aligned(16))) char pt_lds[16*512];     // 8 KB swizzled
  __shared__ unsigned short bm_lds[BI][528];                       // 16.5 KB, padded
  __shared__ __attribute__((aligned(16))) float sdst_win[BI][276]; // 17.3 KB
  __shared__ unsigned short ccum[BI][34];                          // per-chunk excl ranks
  __shared__ float denom_lds[BI];
  __shared__ int base_lds[BI];
  __shared__ int vid_s, gbase_s;

  const int t = threadIdx.x, w = t >> 6, lane = t & 63;
  if (t == 0) vid_s = atomicAdd(ticket, 1);
  __syncthreads();
  const int vid = vid_s;
  const int i0 = vid * BI;

  // ---- phase 1: read 16 adj rows once, pack bitmask words into LDS ----
  #pragma unroll
  for (int rr = 0; rr < 4; ++rr){
    const int i = i0 + w*4 + rr;
    const int4* row4 = (const int4*)(adj + (size_t)i * N);
    #pragma unroll 4
    for (int it = 0; it < 32; ++it){
      const int4 a = row4[it*64 + lane];
      unsigned nib = (unsigned)(a.x>0) | ((unsigned)(a.y>0)<<1) |
                     ((unsigned)(a.z>0)<<2) | ((unsigned)(a.w>0)<<3);
      unsigned word = nib << ((lane & 3) * 4);
      word |= __shfl_xor(word, 1, 64);
      word |= __shfl_xor(word, 2, 64);
      if ((lane & 3) == 0) bm_lds[w*4+rr][it*16 + (lane>>2)] = (unsigned short)word;
    }
  }
  __syncthreads();

  // ---- phase 1b: per-chunk popcounts (thread t: row t>>4, chunks t&15, (t&15)+16) ----
  {
    const int r = t >> 4;
    #pragma unroll
    for (int cc = t & 15; cc < NCHUNK; cc += 16){
      int s = 0;
      #pragma unroll
      for (int jj = 0; jj < 8; ++jj)
        s += __popc(*(const unsigned*)&bm_lds[r][cc*16 + jj*2]);
      ccum[r][cc] = (unsigned short)s;
    }
  }
  __syncthreads();

  // ---- phase 1c + lookback (wave 0) ----
  if (w == 0){
    if (lane < 16){                       // in-place exclusive scan per row
      int run = 0;
      #pragma unroll
      for (int c = 0; c < NCHUNK; ++c){
        int v = ccum[lane][c]; ccum[lane][c] = (unsigned short)run; run += v;
      }
      ccum[lane][NCHUNK] = (unsigned short)run;
    }
    int tot = 0;
    if (lane == 0){                       // block scan over 16 rows + publish aggregate
      int run = 0;
      #pragma unroll
      for (int k = 0; k < BI; ++k){ int c = ccum[k][NCHUNK]; base_lds[k] = run; run += c; }
      tot = run;
      const unsigned pub = ((unsigned)run << 2) | (vid == 0 ? 2u : 1u);
      __hip_atomic_store(&partials[vid], pub, __ATOMIC_RELEASE, __HIP_MEMORY_SCOPE_AGENT);
    }
    unsigned excl = 0;
    if (vid > 0){                         // 64-wide parallel lookback
      int look = vid - 1;
      while (true){
        const int idx = look - lane;
        unsigned v = 2u;                  // sentinel past block 0: inclusive 0
        if (idx >= 0){
          do {
            v = __hip_atomic_load(&partials[idx], __ATOMIC_ACQUIRE, __HIP_MEMORY_SCOPE_AGENT);
          } while ((v & 3u) == 0u);
        }
        const unsigned long long ball = __ballot((v & 3u) == 2u);
        if (ball){
          const int L = __ffsll((unsigned long long)ball) - 1;
          excl += (unsigned)wave_reduce_sum_i((lane <= L) ? (int)(v >> 2) : 0);
          break;
        }
        excl += (unsigned)wave_reduce_sum_i((int)(v >> 2));
        look -= 64;
      }
      if (lane == 0)
        __hip_atomic_store(&partials[vid], ((excl + (unsigned)tot) << 2) | 2u,
                           __ATOMIC_RELEASE, __HIP_MEMORY_SCOPE_AGENT);
    }
    if (lane == 0) gbase_s = (int)excl;
  }
  __syncthreads();

  const int r = t >> 4, g = t & 15;
  const float ab = abias[0];
  const int gbase = gbase_s;
  float dsum = 0.f;
  f32x4 acc = {0.f, 0.f, 0.f, 0.f};

  const int fr = lane & 15, ks = lane >> 4;
  const int fB = w*16 + fr;
  const char* aBase = pt_lds + fr*512;
  const char* bBase = ht_lds + fB*512;
  const int sA = (fr & 7) << 4;
  const int sB = (fB & 7) << 4;
  const int rowbase = gbase + base_lds[r];

  for (int ch = 0; ch < NCHUNK; ++ch){
    const int j0 = ch * BJ;
    __syncthreads();
    // stage ht chunk (bf16 [64][256], swizzled) via global_load_lds
    #pragma unroll
    for (int k = 0; k < 8; ++k){
      const int L = (w*8 + k) * 1024;
      const int f = (w*8 + k) * 2 + (lane >> 5);
      const int b = (lane & 31) * 16;
      const char* src = (const char*)ht + (size_t)f*(N*2) + j0*2 + (b ^ ((f & 7) << 4));
      __builtin_amdgcn_global_load_lds((const __attribute__((address_space(1))) void*)src,
                                       (__attribute__((address_space(3))) void*)(ht_lds + L),
                                       16, 0, 0);
    }
    // per-row chunk window (uniform across the 16 lanes of the row group)
    const int crank = ccum[r][ch];
    const int len   = (int)ccum[r][ch+1] - crank;
    const int q0row = rowbase + crank;
    const int qa    = (q0row & (N-1)) & ~3;
    const int shift = q0row & 3;
    const int nneed = shift + len;
    // stage sdst window (contiguous, row-group-private -> no barrier)
    #pragma unroll
    for (int pas = 0; pas < 5; ++pas){
      const int e0 = pas*64 + g*4;
      if (e0 < nneed)
        *(float4*)&sdst_win[r][e0] = *(const float4*)(sdst2x + qa + e0);
    }
    const int   ilo  = q0row >> 13;
    const float s_lo = ssrc[ilo];
    const float s_hi = ssrc[(q0row + (len > 0 ? len - 1 : 0)) >> 13];
    const int   qhi  = (ilo + 1) << 13;
    // p production
    {
      const unsigned m = bm_lds[r][ch*16 + g];
      const int c = __popc(m);
      int inc = c;
      #pragma unroll
      for (int d = 1; d < 16; d <<= 1){
        int u = __shfl_up(inc, d, 16);
        if (g >= d) inc += u;
      }
      const int qex = inc - c;            // within-chunk exclusive prefix
      const int q0 = q0row + qex;
      unsigned pk[8];
      #pragma unroll
      for (int bb = 0; bb < 16; ++bb){
        float p = 0.f;
        if ((m >> bb) & 1u){
          const int k = __popc(m & ((1u << bb) - 1u));
          const float sd = sdst_win[r][shift + qex + k];
          const float ss = (q0 + k >= qhi) ? s_hi : s_lo;
          float e = ss + sd + ab;
          e = (e > 0.f) ? e : LEAKY * e;
          p = __expf(e);
          dsum += p;
        }
        if (bb & 1) pk[bb >> 1] |= (unsigned)f2bf(p) << 16;
        else        pk[bb >> 1]  = (unsigned)f2bf(p);
      }
      char* pb = pt_lds + r*512;
      const int sw = (r & 7) << 4;
      *(uint4*)(pb + ((g*32)      ^ sw)) = make_uint4(pk[0], pk[1], pk[2], pk[3]);
      *(uint4*)(pb + ((g*32 + 16) ^ sw)) = make_uint4(pk[4], pk[5], pk[6], pk[7]);
    }
    __syncthreads();
    // MFMA: 8 K-steps of 16x16x32
    #pragma unroll
    for (int kk = 0; kk < 8; ++kk){
      const int off = kk*64 + ks*16;
      bf16x8 av = *(const bf16x8*)(aBase + (off ^ sA));
      bf16x8 bv = *(const bf16x8*)(bBase + (off ^ sB));
      acc = __builtin_amdgcn_mfma_f32_16x16x32_bf16(av, bv, acc, 0, 0, 0);
    }
  }
  // denominators
  #pragma unroll
  for (int d = 8; d > 0; d >>= 1) dsum += __shfl_xor(dsum, d, 16);
  if (g == 0) denom_lds[r] = dsum;
  __syncthreads();
  // epilogue: C/D layout col=lane&15, row=(lane>>4)*4+reg
  #pragma unroll
  for (int reg = 0; reg < 4; ++reg){
    const int il = ks*4 + reg;
    const float dn = denom_lds[il];
    float v = (dn > 0.f) ? acc[reg] / dn : 0.f;
    const float o = (v > 0.f) ? v : (__expf(v) - 1.f);
    out[(size_t)(i0 + il)*F + w*16 + fr] = o;
  }
}

extern "C" void kernel_launch(void* const* d_in, const int* in_sizes, int n_in,
                              void* d_out, int out_size, void* d_ws, size_t ws_size,
                              hipStream_t stream){
  const float* x   = (const float*)d_in[0];
  const int*   adj = (const int*)d_in[1];
  const float* ww  = (const float*)d_in[2];
  const float* wb  = (const float*)d_in[3];
  const float* aw  = (const float*)d_in[4];
  const float* ab  = (const float*)d_in[5];
  float* out = (float*)d_out;

  char* ws = (char*)d_ws;
  float*          h        = (float*)(ws);                                  // 2 MB
  unsigned short* ht       = (unsigned short*)(ws + (size_t)N*F*4);         // 1 MB
  float*          ssrc     = (float*)(ws + (size_t)N*F*4 + (size_t)N*F*2);  // 32 KB
  float*          sdst2x   = ssrc + N;                                      // 64 KB
  unsigned*       partials = (unsigned*)(sdst2x + 2*N);                     // 2 KB
  int*            ticket   = (int*)(partials + NBLK);                       // 4 B

  k_h   <<<N/4,  256, 0, stream>>>(x, ww, wb, aw, h, ssrc, sdst2x, partials, ticket);
  k_tr  <<<N/64, 256, 0, stream>>>(h, ht);
  k_main<<<NBLK, 256, 0, stream>>>(adj, ht, ssrc, sdst2x, ab, partials, ticket, out);
}